// Round 9
// baseline (4539.808 us; speedup 1.0000x reference)
//
#include <hip/hip_runtime.h>

// LiquidNeuralNetwork: B=512, S=1024, IN=16, HID=64, OUT=1, N_SUB=4 (RK4).
// Wall = 16368 x T_body. Phase-skewed DUAL chain per wave: chain A's 8
// ds_read_b128 issue mid-body; chain B's whole segment (dots+glue+tanh+write)
// executes before A's data is consumed next body -> each chain's ~120cyc LDS
// round-trip hides under the other's ~140cyc VALU segment. 256 blocks x 64
// thr = 1 wave/CU (sole owner of DS pipe). rtau folded into f16 weights;
// output dot fused into each step's first body on already-resident regs.
// dt constant (linspace); step 0: dt=0 -> h=0; out[0] falls out of the
// fused path (tanh(0)=0 -> bo) automatically.

constexpr int HID  = 64;
constexpr int INF  = 16;
constexpr int SLEN = 1024;

typedef __fp16 h2_t __attribute__((ext_vector_type(2)));

__device__ __forceinline__ float fast_tanh(float x) {
    // tanh(x) = 1 - 2/(e^{2x}+1); exact limits at +/-inf, no clamp needed.
    float e = __builtin_amdgcn_exp2f(x * 2.8853900817779268f); // 2*log2(e)
    float r = __builtin_amdgcn_rcpf(e + 1.0f);
    return fmaf(-2.0f, r, 1.0f);
}

__global__ __launch_bounds__(64, 1) void lnn_skew_kernel(
    const float* __restrict__ x,
    const float* __restrict__ W_in,
    const float* __restrict__ b_in,
    const float* __restrict__ W_hh,
    const float* __restrict__ W_ih,
    const float* __restrict__ bias,
    const float* __restrict__ tau,
    const float* __restrict__ W_out,
    const float* __restrict__ b_out,
    float* __restrict__ out)
{
    const int lane = threadIdx.x;        // hidden index
    const int bA   = blockIdx.x * 2;     // chain A batch index
    const int bB   = bA + 1;             // chain B batch index

    __shared__ __fp16 tA_s[HID];         // 128 B broadcast, chain A
    __shared__ __fp16 tB_s[HID];         // 128 B broadcast, chain B

    const float rtau = 1.0f / tau[lane];

    // --- one-time setup (weights shared by both chains) ---
    h2_t wh[HID / 2];                    // (W_hh row) * rtau, f16 pairs
    {
        const float4* w4 = (const float4*)(W_hh + lane * HID);
        #pragma unroll
        for (int q = 0; q < HID / 4; ++q) {
            float4 v = w4[q];
            wh[2*q+0] = __builtin_amdgcn_cvt_pkrtz(v.x * rtau, v.y * rtau);
            wh[2*q+1] = __builtin_amdgcn_cvt_pkrtz(v.z * rtau, v.w * rtau);
        }
    }
    h2_t wov[HID / 2];                   // W_out row (replicated), f16 pairs
    {
        const float4* o4 = (const float4*)(W_out);
        #pragma unroll
        for (int q = 0; q < HID / 4; ++q) {
            float4 v = o4[q];
            wov[2*q+0] = __builtin_amdgcn_cvt_pkrtz(v.x, v.y);
            wov[2*q+1] = __builtin_amdgcn_cvt_pkrtz(v.z, v.w);
        }
    }
    float Wc[INF];                       // (W_ih @ W_in) row for my unit
    #pragma unroll
    for (int k = 0; k < INF; ++k) Wc[k] = 0.0f;
    float bcomb = 0.0f;
    for (int j = 0; j < HID; ++j) {
        float wij = W_ih[lane * HID + j];
        bcomb = fmaf(wij, b_in[j], bcomb);
        #pragma unroll
        for (int k = 0; k < INF; ++k) Wc[k] = fmaf(wij, W_in[j * INF + k], Wc[k]);
    }
    const float cbase = bcomb + bias[lane];
    const float bo    = b_out[0];

    // dt = 1/1023 for all steps s>=1 (s=0: dt=0 -> h unchanged)
    const float hsub  = (1.0f / 1023.0f) * 0.25f;
    const float hsubh = 0.5f * hsub;
    const float h6    = hsub * (1.0f / 6.0f);

    // --- per-chain state ---
    float hA = 0.f, hB = 0.f, yA = 0.f, yB = 0.f, ksA = 0.f, ksB = 0.f;
    float crA = 0.f, crB = 0.f;          // c_step * rtau per chain
    uint4 rA[8], rB[8];                  // in-flight broadcast registers

    auto dots = [&](const uint4* r, const h2_t* g, float seed) -> float {
        float a0 = seed, a1 = 0.f, a2 = 0.f, a3 = 0.f;
        #pragma unroll
        for (int q = 0; q < 8; ++q) {
            a0 = __builtin_amdgcn_fdot2(__builtin_bit_cast(h2_t, r[q].x), g[4*q+0], a0, false);
            a1 = __builtin_amdgcn_fdot2(__builtin_bit_cast(h2_t, r[q].y), g[4*q+1], a1, false);
            a2 = __builtin_amdgcn_fdot2(__builtin_bit_cast(h2_t, r[q].z), g[4*q+2], a2, false);
            a3 = __builtin_amdgcn_fdot2(__builtin_bit_cast(h2_t, r[q].w), g[4*q+3], a3, false);
        }
        return (a0 + a1) + (a2 + a3);
    };
    auto rdA = [&]() {
        const uint4* p = (const uint4*)tA_s;
        #pragma unroll
        for (int q = 0; q < 8; ++q) rA[q] = p[q];
    };
    auto rdB = [&]() {
        const uint4* p = (const uint4*)tB_s;
        #pragma unroll
        for (int q = 0; q < 8; ++q) rB[q] = p[q];
    };
    // RK4 glue: e = eval index within substep (k1..k4)
    auto glue = [&](int e, float f, float& y, float& ks, float& h) {
        if (e == 0)      { ks = f;                 y = fmaf(hsubh, f, h); }
        else if (e == 1) { ks = fmaf(2.0f, f, ks); y = fmaf(hsubh, f, h); }
        else if (e == 2) { ks = fmaf(2.0f, f, ks); y = fmaf(hsub,  f, h); }
        else             { ks += f; h = fmaf(h6, ks, h); y = h; }
    };

    const float4* xrA = (const float4*)(x + (size_t)bA * SLEN * INF);
    const float4* xrB = (const float4*)(x + (size_t)bB * SLEN * INF);
    float* orA = out + (size_t)bA * SLEN;
    float* orB = out + (size_t)bB * SLEN;

    // skewed dual-eval body: A consumes rA (issued last body, covered by
    // last body's B segment), reissues rA (covered by this body's B seg).
    auto body = [&](int e, bool fuse, int s) {
        // ---- chain A segment ----
        float fA = dots(rA, wh, fmaf(-rtau, yA, crA));
        if (fuse) {                       // prev step's output, same regs
            float os = dots(rA, wov, 0.f);
            if (lane == 0) orA[s - 1] = os + bo;
        }
        glue(e, fA, yA, ksA, hA);
        tA_s[lane] = (__fp16)fast_tanh(yA);
        rdA();                            // 8 ds_read_b128, data used NEXT body
        // ---- chain B segment (covers rA latency) ----
        float fB = dots(rB, wh, fmaf(-rtau, yB, crB));
        if (fuse) {
            float os = dots(rB, wov, 0.f);
            if (lane == 0) orB[s - 1] = os + bo;
        }
        glue(e, fB, yB, ksB, hB);
        tB_s[lane] = (__fp16)fast_tanh(yB);
        rdB();                            // covered by next body's A segment
    };

    // --- prologue: prime broadcasts with tanh(0)=0 and issue first reads ---
    tA_s[lane] = (__fp16)0.0f;
    tB_s[lane] = (__fp16)0.0f;
    rdA(); rdB();

    // prefetch x for s=1
    float4 xa0 = xrA[4], xa1 = xrA[5], xa2 = xrA[6], xa3 = xrA[7];
    float4 xb0 = xrB[4], xb1 = xrB[5], xb2 = xrB[6], xb3 = xrB[7];

    for (int s = 1; s < SLEN; ++s) {
        // c*rtau per chain from prefetched regs (off critical path)
        {
            float c1 = fmaf(xa0.x, Wc[0], fmaf(xa0.y, Wc[1],
                       fmaf(xa0.z, Wc[2], fmaf(xa0.w, Wc[3], cbase))));
            float c2 = fmaf(xa1.x, Wc[4], fmaf(xa1.y, Wc[5],
                       fmaf(xa1.z, Wc[6], xa1.w * Wc[7])));
            float c3 = fmaf(xa2.x, Wc[8], fmaf(xa2.y, Wc[9],
                       fmaf(xa2.z, Wc[10], xa2.w * Wc[11])));
            float c4 = fmaf(xa3.x, Wc[12], fmaf(xa3.y, Wc[13],
                       fmaf(xa3.z, Wc[14], xa3.w * Wc[15])));
            crA = ((c1 + c2) + (c3 + c4)) * rtau;
            float d1 = fmaf(xb0.x, Wc[0], fmaf(xb0.y, Wc[1],
                       fmaf(xb0.z, Wc[2], fmaf(xb0.w, Wc[3], cbase))));
            float d2 = fmaf(xb1.x, Wc[4], fmaf(xb1.y, Wc[5],
                       fmaf(xb1.z, Wc[6], xb1.w * Wc[7])));
            float d3 = fmaf(xb2.x, Wc[8], fmaf(xb2.y, Wc[9],
                       fmaf(xb2.z, Wc[10], xb2.w * Wc[11])));
            float d4 = fmaf(xb3.x, Wc[12], fmaf(xb3.y, Wc[13],
                       fmaf(xb3.z, Wc[14], xb3.w * Wc[15])));
            crB = ((d1 + d2) + (d3 + d4)) * rtau;
        }
        // prefetch next step's x (hidden behind 16 bodies)
        {
            int sn = (s < SLEN - 1) ? (s + 1) : (SLEN - 1);
            xa0 = xrA[sn*4+0]; xa1 = xrA[sn*4+1];
            xa2 = xrA[sn*4+2]; xa3 = xrA[sn*4+3];
            xb0 = xrB[sn*4+0]; xb1 = xrB[sn*4+1];
            xb2 = xrB[sn*4+2]; xb3 = xrB[sn*4+3];
        }

        #pragma unroll 1
        for (int sub = 0; sub < 4; ++sub) {
            body(0, sub == 0, s);        // k1 (+ fused prev-step output)
            body(1, false, s);           // k2
            body(2, false, s);           // k3
            body(3, false, s);           // k4 + h update
        }
    }

    // epilogue: rA/rB hold broadcast of tanh(h_final) from the last body
    {
        float os = dots(rA, wov, 0.f);
        if (lane == 0) orA[SLEN - 1] = os + bo;
        float osb = dots(rB, wov, 0.f);
        if (lane == 0) orB[SLEN - 1] = osb + bo;
    }
}

extern "C" void kernel_launch(void* const* d_in, const int* in_sizes, int n_in,
                              void* d_out, int out_size, void* d_ws, size_t ws_size,
                              hipStream_t stream) {
    const float* x     = (const float*)d_in[0];
    const float* W_in  = (const float*)d_in[1];
    const float* b_in  = (const float*)d_in[2];
    const float* W_hh  = (const float*)d_in[3];
    const float* W_ih  = (const float*)d_in[4];
    const float* bias  = (const float*)d_in[5];
    const float* tau   = (const float*)d_in[6];
    const float* W_out = (const float*)d_in[7];
    const float* b_out = (const float*)d_in[8];
    float* out = (float*)d_out;

    lnn_skew_kernel<<<256, 64, 0, stream>>>(x, W_in, b_in, W_hh, W_ih, bias,
                                            tau, W_out, b_out, out);
}

// Round 10
// 4528.112 us; speedup vs baseline: 1.0026x; 1.0026x over previous
//
#include <hip/hip_runtime.h>

// LiquidNeuralNetwork: B=512, S=1024, IN=16, HID=64, OUT=1, N_SUB=4 (RK4).
// Phase-skewed DUAL chain per wave: chain A's 8 ds_read_b128 issue mid-body,
// pinned by sched_barrier(0) so they CANNOT sink to their use site; chain B's
// whole segment (dots+glue+tanh+write) executes between A's read-issue and
// A's consumption next body -> the ~130cyc LDS round-trip overlaps B's VALU.
// Round 9 failed because the compiler sank the reads (VGPR=84 proved the
// in-flight arrays never went live); the barriers force the pipeline.
// 256 blocks x 64 thr = 1 wave/CU. rtau folded into f16 weights; output dot
// fused into each step's first body. dt constant; step 0: dt=0 -> out[0]=bo.

constexpr int HID  = 64;
constexpr int INF  = 16;
constexpr int SLEN = 1024;

typedef __fp16 h2_t __attribute__((ext_vector_type(2)));

__device__ __forceinline__ float fast_tanh(float x) {
    // tanh(x) = 1 - 2/(e^{2x}+1); exact limits at +/-inf, no clamp needed.
    float e = __builtin_amdgcn_exp2f(x * 2.8853900817779268f); // 2*log2(e)
    float r = __builtin_amdgcn_rcpf(e + 1.0f);
    return fmaf(-2.0f, r, 1.0f);
}

__global__ __launch_bounds__(64, 1) void lnn_skew2_kernel(
    const float* __restrict__ x,
    const float* __restrict__ W_in,
    const float* __restrict__ b_in,
    const float* __restrict__ W_hh,
    const float* __restrict__ W_ih,
    const float* __restrict__ bias,
    const float* __restrict__ tau,
    const float* __restrict__ W_out,
    const float* __restrict__ b_out,
    float* __restrict__ out)
{
    const int lane = threadIdx.x;        // hidden index
    const int bA   = blockIdx.x * 2;     // chain A batch index
    const int bB   = bA + 1;             // chain B batch index

    __shared__ __fp16 tA_s[HID];         // 128 B broadcast, chain A
    __shared__ __fp16 tB_s[HID];         // 128 B broadcast, chain B

    const float rtau = 1.0f / tau[lane];

    // --- one-time setup (weights shared by both chains) ---
    h2_t wh[HID / 2];                    // (W_hh row) * rtau, f16 pairs
    {
        const float4* w4 = (const float4*)(W_hh + lane * HID);
        #pragma unroll
        for (int q = 0; q < HID / 4; ++q) {
            float4 v = w4[q];
            wh[2*q+0] = __builtin_amdgcn_cvt_pkrtz(v.x * rtau, v.y * rtau);
            wh[2*q+1] = __builtin_amdgcn_cvt_pkrtz(v.z * rtau, v.w * rtau);
        }
    }
    h2_t wov[HID / 2];                   // W_out row (replicated), f16 pairs
    {
        const float4* o4 = (const float4*)(W_out);
        #pragma unroll
        for (int q = 0; q < HID / 4; ++q) {
            float4 v = o4[q];
            wov[2*q+0] = __builtin_amdgcn_cvt_pkrtz(v.x, v.y);
            wov[2*q+1] = __builtin_amdgcn_cvt_pkrtz(v.z, v.w);
        }
    }
    float Wc[INF];                       // (W_ih @ W_in) row for my unit
    #pragma unroll
    for (int k = 0; k < INF; ++k) Wc[k] = 0.0f;
    float bcomb = 0.0f;
    for (int j = 0; j < HID; ++j) {
        float wij = W_ih[lane * HID + j];
        bcomb = fmaf(wij, b_in[j], bcomb);
        #pragma unroll
        for (int k = 0; k < INF; ++k) Wc[k] = fmaf(wij, W_in[j * INF + k], Wc[k]);
    }
    const float cbase = bcomb + bias[lane];
    const float bo    = b_out[0];

    // dt = 1/1023 for all steps s>=1 (s=0: dt=0 -> h unchanged)
    const float hsub  = (1.0f / 1023.0f) * 0.25f;
    const float hsubh = 0.5f * hsub;
    const float h6    = hsub * (1.0f / 6.0f);

    // --- per-chain state ---
    float hA = 0.f, hB = 0.f, yA = 0.f, yB = 0.f, ksA = 0.f, ksB = 0.f;
    float crA = 0.f, crB = 0.f;          // c_step * rtau per chain
    uint4 rA[8], rB[8];                  // in-flight broadcast registers

    auto dots = [&](const uint4* r, const h2_t* g, float seed) -> float {
        float a0 = seed, a1 = 0.f, a2 = 0.f, a3 = 0.f;
        #pragma unroll
        for (int q = 0; q < 8; ++q) {
            a0 = __builtin_amdgcn_fdot2(__builtin_bit_cast(h2_t, r[q].x), g[4*q+0], a0, false);
            a1 = __builtin_amdgcn_fdot2(__builtin_bit_cast(h2_t, r[q].y), g[4*q+1], a1, false);
            a2 = __builtin_amdgcn_fdot2(__builtin_bit_cast(h2_t, r[q].z), g[4*q+2], a2, false);
            a3 = __builtin_amdgcn_fdot2(__builtin_bit_cast(h2_t, r[q].w), g[4*q+3], a3, false);
        }
        return (a0 + a1) + (a2 + a3);
    };
    auto rdA = [&]() {
        const uint4* p = (const uint4*)tA_s;
        #pragma unroll
        for (int q = 0; q < 8; ++q) rA[q] = p[q];
        __builtin_amdgcn_sched_barrier(0);   // pin: reads may NOT sink below
    };
    auto rdB = [&]() {
        const uint4* p = (const uint4*)tB_s;
        #pragma unroll
        for (int q = 0; q < 8; ++q) rB[q] = p[q];
        __builtin_amdgcn_sched_barrier(0);   // pin: reads may NOT sink below
    };
    // RK4 glue: e = eval index within substep (k1..k4), compile-time const
    auto glue = [&](int e, float f, float& y, float& ks, float& h) {
        if (e == 0)      { ks = f;                 y = fmaf(hsubh, f, h); }
        else if (e == 1) { ks = fmaf(2.0f, f, ks); y = fmaf(hsubh, f, h); }
        else if (e == 2) { ks = fmaf(2.0f, f, ks); y = fmaf(hsub,  f, h); }
        else             { ks += f; h = fmaf(h6, ks, h); y = h; }
    };

    const float4* xrA = (const float4*)(x + (size_t)bA * SLEN * INF);
    const float4* xrB = (const float4*)(x + (size_t)bB * SLEN * INF);
    float* orA = out + (size_t)bA * SLEN;
    float* orB = out + (size_t)bB * SLEN;

    // skewed dual-eval body: A consumes rA (issued last body, latency covered
    // by last body's B segment), then reissues rA (covered by this body's B).
    auto body = [&](int e, bool fuse, int s) {
        // ---- chain A segment ----
        float fA = dots(rA, wh, fmaf(-rtau, yA, crA));
        if (fuse) {                       // prev step's output, same regs
            float os = dots(rA, wov, 0.f);
            if (lane == 0) orA[s - 1] = os + bo;
        }
        glue(e, fA, yA, ksA, hA);
        tA_s[lane] = (__fp16)fast_tanh(yA);
        rdA();                            // 8 ds_read_b128, used NEXT body
        // ---- chain B segment (covers rA round-trip) ----
        float fB = dots(rB, wh, fmaf(-rtau, yB, crB));
        if (fuse) {
            float os = dots(rB, wov, 0.f);
            if (lane == 0) orB[s - 1] = os + bo;
        }
        glue(e, fB, yB, ksB, hB);
        tB_s[lane] = (__fp16)fast_tanh(yB);
        rdB();                            // covered by next body's A segment
    };

    // --- prologue: prime broadcasts with tanh(0)=0 and issue first reads ---
    tA_s[lane] = (__fp16)0.0f;
    tB_s[lane] = (__fp16)0.0f;
    rdA(); rdB();

    // prefetch x for s=1
    float4 xa0 = xrA[4], xa1 = xrA[5], xa2 = xrA[6], xa3 = xrA[7];
    float4 xb0 = xrB[4], xb1 = xrB[5], xb2 = xrB[6], xb3 = xrB[7];

    for (int s = 1; s < SLEN; ++s) {
        // c*rtau per chain from prefetched regs (off critical path)
        {
            float c1 = fmaf(xa0.x, Wc[0], fmaf(xa0.y, Wc[1],
                       fmaf(xa0.z, Wc[2], fmaf(xa0.w, Wc[3], cbase))));
            float c2 = fmaf(xa1.x, Wc[4], fmaf(xa1.y, Wc[5],
                       fmaf(xa1.z, Wc[6], xa1.w * Wc[7])));
            float c3 = fmaf(xa2.x, Wc[8], fmaf(xa2.y, Wc[9],
                       fmaf(xa2.z, Wc[10], xa2.w * Wc[11])));
            float c4 = fmaf(xa3.x, Wc[12], fmaf(xa3.y, Wc[13],
                       fmaf(xa3.z, Wc[14], xa3.w * Wc[15])));
            crA = ((c1 + c2) + (c3 + c4)) * rtau;
            float d1 = fmaf(xb0.x, Wc[0], fmaf(xb0.y, Wc[1],
                       fmaf(xb0.z, Wc[2], fmaf(xb0.w, Wc[3], cbase))));
            float d2 = fmaf(xb1.x, Wc[4], fmaf(xb1.y, Wc[5],
                       fmaf(xb1.z, Wc[6], xb1.w * Wc[7])));
            float d3 = fmaf(xb2.x, Wc[8], fmaf(xb2.y, Wc[9],
                       fmaf(xb2.z, Wc[10], xb2.w * Wc[11])));
            float d4 = fmaf(xb3.x, Wc[12], fmaf(xb3.y, Wc[13],
                       fmaf(xb3.z, Wc[14], xb3.w * Wc[15])));
            crB = ((d1 + d2) + (d3 + d4)) * rtau;
        }
        // prefetch next step's x (hidden behind 16 bodies)
        {
            int sn = (s < SLEN - 1) ? (s + 1) : (SLEN - 1);
            xa0 = xrA[sn*4+0]; xa1 = xrA[sn*4+1];
            xa2 = xrA[sn*4+2]; xa3 = xrA[sn*4+3];
            xb0 = xrB[sn*4+0]; xb1 = xrB[sn*4+1];
            xb2 = xrB[sn*4+2]; xb3 = xrB[sn*4+3];
        }

        // unroll 1: rA/rB must be loop-carried registers across the backedge
        #pragma unroll 1
        for (int sub = 0; sub < 4; ++sub) {
            body(0, sub == 0, s);        // k1 (+ fused prev-step output)
            body(1, false, s);           // k2
            body(2, false, s);           // k3
            body(3, false, s);           // k4 + h update
        }
    }

    // epilogue: rA/rB hold broadcast of tanh(h_final) from the last body
    {
        float os = dots(rA, wov, 0.f);
        if (lane == 0) orA[SLEN - 1] = os + bo;
        float osb = dots(rB, wov, 0.f);
        if (lane == 0) orB[SLEN - 1] = osb + bo;
    }
}

extern "C" void kernel_launch(void* const* d_in, const int* in_sizes, int n_in,
                              void* d_out, int out_size, void* d_ws, size_t ws_size,
                              hipStream_t stream) {
    const float* x     = (const float*)d_in[0];
    const float* W_in  = (const float*)d_in[1];
    const float* b_in  = (const float*)d_in[2];
    const float* W_hh  = (const float*)d_in[3];
    const float* W_ih  = (const float*)d_in[4];
    const float* bias  = (const float*)d_in[5];
    const float* tau   = (const float*)d_in[6];
    const float* W_out = (const float*)d_in[7];
    const float* b_out = (const float*)d_in[8];
    float* out = (float*)d_out;

    lnn_skew2_kernel<<<256, 64, 0, stream>>>(x, W_in, b_in, W_hh, W_ih, bias,
                                             tau, W_out, b_out, out);
}

// Round 12
// 3102.389 us; speedup vs baseline: 1.4633x; 1.4596x over previous
//
#include <hip/hip_runtime.h>

// LiquidNeuralNetwork: B=512, S=1024, IN=16, HID=64, OUT=1, N_SUB=4 (RK4).
// G=1 chain per wave (512 blocks x 64 thr), plain C++ LDS broadcast (compiler
// owns the waitcnts -- sound; rounds 9-11 proved hand-rolled async staging is
// not). Chain micro-optimized per round-9 forensics (333 cyc/eval measured):
//   - rtau folded into f16 W_hh  -> no post-dot multiply
//   - acc0 seeded with fmaf(-rtau,y,c*rtau), computed parallel to tanh
//   - running-ks RK4 glue (ks updates overlap the next eval)
//   - fdot2 (v_dot2_f32_f16) inner product, 1 ds_write_b16 + 8 ds_read_b128
//   - output dot fused into next step's first eval (same broadcast regs)
// dt constant (linspace); step 0 has dt=0 -> h stays 0, out[0]=b_out.

constexpr int HID  = 64;
constexpr int INF  = 16;
constexpr int SLEN = 1024;

typedef __fp16 h2_t __attribute__((ext_vector_type(2)));

__device__ __forceinline__ float fast_tanh(float x) {
    // tanh(x) = 1 - 2/(e^{2x}+1); exact limits at +/-inf, no clamp needed.
    float e = __builtin_amdgcn_exp2f(x * 2.8853900817779268f); // 2*log2(e)
    float r = __builtin_amdgcn_rcpf(e + 1.0f);
    return fmaf(-2.0f, r, 1.0f);
}

__global__ __launch_bounds__(64, 1) void lnn_lean_kernel(
    const float* __restrict__ x,
    const float* __restrict__ W_in,
    const float* __restrict__ b_in,
    const float* __restrict__ W_hh,
    const float* __restrict__ W_ih,
    const float* __restrict__ bias,
    const float* __restrict__ tau,
    const float* __restrict__ W_out,
    const float* __restrict__ b_out,
    float* __restrict__ out)
{
    const int lane = threadIdx.x;        // hidden index
    const int b    = blockIdx.x;         // batch index

    __shared__ __fp16 th_s[HID];         // 128 B f16 broadcast, wave-private

    const float rtau = 1.0f / tau[lane];

    // --- one-time setup ---
    h2_t wh[HID / 2];                    // (W_hh row) * rtau, f16 pairs
    {
        const float4* w4 = (const float4*)(W_hh + lane * HID);
        #pragma unroll
        for (int q = 0; q < HID / 4; ++q) {
            float4 v = w4[q];
            wh[2*q+0] = __builtin_amdgcn_cvt_pkrtz(v.x * rtau, v.y * rtau);
            wh[2*q+1] = __builtin_amdgcn_cvt_pkrtz(v.z * rtau, v.w * rtau);
        }
    }
    h2_t wov[HID / 2];                   // W_out row (replicated), f16 pairs
    {
        const float4* o4 = (const float4*)(W_out);
        #pragma unroll
        for (int q = 0; q < HID / 4; ++q) {
            float4 v = o4[q];
            wov[2*q+0] = __builtin_amdgcn_cvt_pkrtz(v.x, v.y);
            wov[2*q+1] = __builtin_amdgcn_cvt_pkrtz(v.z, v.w);
        }
    }
    float Wc[INF];                       // (W_ih @ W_in) row for my unit
    #pragma unroll
    for (int k = 0; k < INF; ++k) Wc[k] = 0.0f;
    float bcomb = 0.0f;
    for (int j = 0; j < HID; ++j) {
        float wij = W_ih[lane * HID + j];
        bcomb = fmaf(wij, b_in[j], bcomb);
        #pragma unroll
        for (int k = 0; k < INF; ++k) Wc[k] = fmaf(wij, W_in[j * INF + k], Wc[k]);
    }
    const float cbase = bcomb + bias[lane];
    const float bo    = b_out[0];

    float cr = 0.0f;                     // c_step * rtau

    // ode_f(y) = dot(wh, tanh_bcast) + (c - y)*rtau  (rtau folded everywhere)
    auto odef = [&](float y) -> float {
        float cmy = fmaf(-rtau, y, cr);      // parallel to tanh chain
        float t = fast_tanh(y);
        th_s[lane] = (__fp16)t;              // 1 ds_write_b16, intra-wave
        float a0 = cmy, a1 = 0.f, a2 = 0.f, a3 = 0.f;
        const uint4* t4 = (const uint4*)th_s;
        #pragma unroll
        for (int q = 0; q < 8; ++q) {        // 8x ds_read_b128
            uint4 r = t4[q];
            a0 = __builtin_amdgcn_fdot2(__builtin_bit_cast(h2_t, r.x), wh[4*q+0], a0, false);
            a1 = __builtin_amdgcn_fdot2(__builtin_bit_cast(h2_t, r.y), wh[4*q+1], a1, false);
            a2 = __builtin_amdgcn_fdot2(__builtin_bit_cast(h2_t, r.z), wh[4*q+2], a2, false);
            a3 = __builtin_amdgcn_fdot2(__builtin_bit_cast(h2_t, r.w), wh[4*q+3], a3, false);
        }
        return (a0 + a1) + (a2 + a3);
    };

    // same, but also emits os = wov . tanh_bcast (previous step's output)
    auto odef_out = [&](float y, float& os) -> float {
        float cmy = fmaf(-rtau, y, cr);
        float t = fast_tanh(y);
        th_s[lane] = (__fp16)t;
        float a0 = cmy, a1 = 0.f, a2 = 0.f, a3 = 0.f;
        float o0 = 0.f, o1 = 0.f, o2 = 0.f, o3 = 0.f;
        const uint4* t4 = (const uint4*)th_s;
        #pragma unroll
        for (int q = 0; q < 8; ++q) {        // same 8 reads feed both dots
            uint4 r = t4[q];
            h2_t px = __builtin_bit_cast(h2_t, r.x);
            h2_t py = __builtin_bit_cast(h2_t, r.y);
            h2_t pz = __builtin_bit_cast(h2_t, r.z);
            h2_t pw = __builtin_bit_cast(h2_t, r.w);
            a0 = __builtin_amdgcn_fdot2(px, wh[4*q+0], a0, false);
            a1 = __builtin_amdgcn_fdot2(py, wh[4*q+1], a1, false);
            a2 = __builtin_amdgcn_fdot2(pz, wh[4*q+2], a2, false);
            a3 = __builtin_amdgcn_fdot2(pw, wh[4*q+3], a3, false);
            o0 = __builtin_amdgcn_fdot2(px, wov[4*q+0], o0, false);
            o1 = __builtin_amdgcn_fdot2(py, wov[4*q+1], o1, false);
            o2 = __builtin_amdgcn_fdot2(pz, wov[4*q+2], o2, false);
            o3 = __builtin_amdgcn_fdot2(pw, wov[4*q+3], o3, false);
        }
        os = (o0 + o1) + (o2 + o3);
        return (a0 + a1) + (a2 + a3);
    };

    float h = 0.0f;
    // dt = 1/1023 for all steps s>=1 (s=0: dt=0 -> h unchanged; out[0]=bo)
    const float hsub  = (1.0f / 1023.0f) * 0.25f;
    const float hsubh = 0.5f * hsub;
    const float h6    = hsub * (1.0f / 6.0f);

    const float4* xrow = (const float4*)(x + (size_t)b * SLEN * INF);
    float* orow = out + (size_t)b * SLEN;

    if (lane == 0) orow[0] = bo;             // h=0 after step 0

    // prefetch x for s=1
    float4 xp0 = xrow[4], xp1 = xrow[5], xp2 = xrow[6], xp3 = xrow[7];

    for (int s = 1; s < SLEN; ++s) {
        // c*rtau for this step from prefetched regs (4 parallel FMA trees)
        {
            float cA = fmaf(xp0.x, Wc[0], fmaf(xp0.y, Wc[1],
                       fmaf(xp0.z, Wc[2], fmaf(xp0.w, Wc[3], cbase))));
            float cB = fmaf(xp1.x, Wc[4], fmaf(xp1.y, Wc[5],
                       fmaf(xp1.z, Wc[6], xp1.w * Wc[7])));
            float cC = fmaf(xp2.x, Wc[8], fmaf(xp2.y, Wc[9],
                       fmaf(xp2.z, Wc[10], xp2.w * Wc[11])));
            float cD = fmaf(xp3.x, Wc[12], fmaf(xp3.y, Wc[13],
                       fmaf(xp3.z, Wc[14], xp3.w * Wc[15])));
            cr = ((cA + cB) + (cC + cD)) * rtau;
        }
        // prefetch next step's x (hidden behind the 16 evals below)
        {
            int sn = (s < SLEN - 1) ? (s + 1) : (SLEN - 1);
            xp0 = xrow[sn*4+0]; xp1 = xrow[sn*4+1];
            xp2 = xrow[sn*4+2]; xp3 = xrow[sn*4+3];
        }

        // substep 0: first eval also yields previous step's output
        {
            float os;
            float k1 = odef_out(h, os);
            if (lane == 0) orow[s - 1] = os + bo;
            float ks = k1;
            float k2 = odef(fmaf(hsubh, k1, h)); ks = fmaf(2.0f, k2, ks);
            float k3 = odef(fmaf(hsubh, k2, h)); ks = fmaf(2.0f, k3, ks);
            float k4 = odef(fmaf(hsub,  k3, h)); ks += k4;
            h = fmaf(h6, ks, h);
        }
        #pragma unroll
        for (int sub = 1; sub < 4; ++sub) {
            float k1 = odef(h);
            float ks = k1;
            float k2 = odef(fmaf(hsubh, k1, h)); ks = fmaf(2.0f, k2, ks);
            float k3 = odef(fmaf(hsubh, k2, h)); ks = fmaf(2.0f, k3, ks);
            float k4 = odef(fmaf(hsub,  k3, h)); ks += k4;
            h = fmaf(h6, ks, h);
        }
    }

    // epilogue: out[1023] = wov . tanh(h_final) + bo
    {
        float t = fast_tanh(h);
        th_s[lane] = (__fp16)t;
        float o0 = 0.f, o1 = 0.f, o2 = 0.f, o3 = 0.f;
        const uint4* t4 = (const uint4*)th_s;
        #pragma unroll
        for (int q = 0; q < 8; ++q) {
            uint4 r = t4[q];
            o0 = __builtin_amdgcn_fdot2(__builtin_bit_cast(h2_t, r.x), wov[4*q+0], o0, false);
            o1 = __builtin_amdgcn_fdot2(__builtin_bit_cast(h2_t, r.y), wov[4*q+1], o1, false);
            o2 = __builtin_amdgcn_fdot2(__builtin_bit_cast(h2_t, r.z), wov[4*q+2], o2, false);
            o3 = __builtin_amdgcn_fdot2(__builtin_bit_cast(h2_t, r.w), wov[4*q+3], o3, false);
        }
        if (lane == 0) orow[SLEN - 1] = (o0 + o1) + (o2 + o3) + bo;
    }
}

extern "C" void kernel_launch(void* const* d_in, const int* in_sizes, int n_in,
                              void* d_out, int out_size, void* d_ws, size_t ws_size,
                              hipStream_t stream) {
    const float* x     = (const float*)d_in[0];
    const float* W_in  = (const float*)d_in[1];
    const float* b_in  = (const float*)d_in[2];
    const float* W_hh  = (const float*)d_in[3];
    const float* W_ih  = (const float*)d_in[4];
    const float* bias  = (const float*)d_in[5];
    const float* tau   = (const float*)d_in[6];
    const float* W_out = (const float*)d_in[7];
    const float* b_out = (const float*)d_in[8];
    float* out = (float*)d_out;

    lnn_lean_kernel<<<512, 64, 0, stream>>>(x, W_in, b_in, W_hh, W_ih, bias,
                                            tau, W_out, b_out, out);
}